// Round 1
// baseline (261.747 us; speedup 1.0000x reference)
//
#include <hip/hip_runtime.h>

#define NROWS   262144
#define NCODES  1024
#define DIM     64
#define LIST_CAP 65536u
#define STEPS   16       // 1024 codes / 64 per step
#define TILES   4        // 16-code MFMA tiles per step
#define RSTRIDE 144      // LDS bytes per code row: 128 data + 16 pad (bank-spread)
#define BUFB    (TILES * 16 * RSTRIDE)   // 9216 B per buffer

typedef _Float16 half8 __attribute__((ext_vector_type(8)));
typedef __attribute__((ext_vector_type(4))) float f32x4;

#define MFMA16(acc, a, b) acc = __builtin_amdgcn_mfma_f32_16x16x32_f16(a, b, acc, 0, 0, 0)

// ---------------------------------------------------------------------------
// Prep: unchanged (bit-identical arithmetic to the validated version).
// ctrl[0] = max ||c - fp16(c)||^2 bits (atomicMax), ctrl[1] = flag counter.
// ---------------------------------------------------------------------------
__global__ __launch_bounds__(256) void vq_prep(const float* __restrict__ cb,
                                               float* __restrict__ hcsq,
                                               _Float16* __restrict__ Ch,
                                               unsigned* ctrl) {
    const int k = blockIdx.x * 256 + threadIdx.x;   // 0..1023
    const float4* row = (const float4*)(cb + (size_t)k * DIM);
    _Float16* co = Ch + (size_t)k * DIM;
    float s = 0.f, r2 = 0.f;
#pragma unroll
    for (int i = 0; i < 8; ++i) {
        float4 a = row[2 * i], b = row[2 * i + 1];
        float v[8] = {a.x, a.y, a.z, a.w, b.x, b.y, b.z, b.w};
        union { half8 f; _Float16 e[8]; } uh;
#pragma unroll
        for (int j = 0; j < 8; ++j) {
            float c = v[j];
            s += c * c;                    // sequential chain (matches r4/r1)
            _Float16 h = (_Float16)c;      // RNE
            uh.e[j] = h;
            float d = c - (float)h;        // true residual
            r2 += d * d;
        }
        *(half8*)(co + i * 8) = uh.f;
    }
    hcsq[k] = 0.5f * s;
    float w = r2;
#pragma unroll
    for (int off = 1; off < 64; off <<= 1) w = fmaxf(w, __shfl_xor(w, off));
    if ((threadIdx.x & 63) == 0) atomicMax(ctrl + 0, __float_as_uint(w));
}

// ---------------------------------------------------------------------------
// Main: same math/margin as the validated r4 kernel (fp16 2-term, fused top-2,
// rigorous fat margin 2(||x||E + 1e-3)). Structural changes this round:
//   1. Tile-level software pipeline: acc + B-fragment double-buffered; the
//      selection of tile t-1 issues between the MFMA groups of tile t, and
//      the step-boundary pending selection covers the first ds_read latency.
//      A dummy -INF pending at step 0 keeps the pipeline branch-free
//      (strict '>' fails and fmed3(-inf,b,s)=s, so it's a provable no-op).
//   2. -hc folded into the MFMA accumulator init (C = -0.5||c||^2): removes
//      the per-candidate v_sub. Rounding-path delta ~1e-5, << 1e-3 slack.
//   3. Selection tracks the wave-uniform tile index (code = tile*16 + m,
//      reconstructed in the epilogue) so the index cndmask uses an SGPR.
// ---------------------------------------------------------------------------
#define SELECT(aa, ab, tl)                                                        \
    {                                                                             \
        const int _tl = (tl);                                                     \
        _Pragma("unroll")                                                         \
        for (int r = 0; r < 4; ++r) {                                             \
            float s0 = (aa)[r];                                                   \
            bool g0 = s0 > best[0][r];                                            \
            second[0][r] = __builtin_amdgcn_fmed3f(s0, best[0][r], second[0][r]); \
            best[0][r] = g0 ? s0 : best[0][r];                                    \
            btile[0][r] = g0 ? _tl : btile[0][r];                                 \
            float s1 = (ab)[r];                                                   \
            bool g1 = s1 > best[1][r];                                            \
            second[1][r] = __builtin_amdgcn_fmed3f(s1, best[1][r], second[1][r]); \
            best[1][r] = g1 ? s1 : best[1][r];                                    \
            btile[1][r] = g1 ? _tl : btile[1][r];                                 \
        }                                                                         \
    }

#define TILE_MFMA(acc0, acc1, cc0, cc1, hcv)                  \
    acc0 = (f32x4){-(hcv), -(hcv), -(hcv), -(hcv)};           \
    acc1 = acc0;                                              \
    MFMA16(acc0, xh[0][0], cc0); MFMA16(acc1, xh[1][0], cc0); \
    MFMA16(acc0, xh[0][1], cc1); MFMA16(acc1, xh[1][1], cc1); \
    MFMA16(acc0, xl[0][0], cc0); MFMA16(acc1, xl[1][0], cc0); \
    MFMA16(acc0, xl[0][1], cc1); MFMA16(acc1, xl[1][1], cc1);

__global__ __launch_bounds__(256) void vq_main(const float* __restrict__ inputs,
                                               const float* __restrict__ cb,
                                               const float* __restrict__ hcsq,
                                               const _Float16* __restrict__ Ch,
                                               const unsigned* ctrl,
                                               float* __restrict__ out,
                                               unsigned* cnt,
                                               unsigned* __restrict__ list) {
    __shared__ __align__(16) char lds[2 * BUFB];
    __shared__ float shc[NCODES];
    const int tid = threadIdx.x;
    const int lane = tid & 63;
    const int wave = tid >> 6;
    const int m = lane & 15;   // A row-in-tile / B code-in-tile / D col
    const int q = lane >> 4;   // k-quad
    const size_t rowbase = (size_t)blockIdx.x * 128 + (size_t)wave * 32;

    for (int i = tid; i < NCODES; i += 256) shc[i] = hcsq[i];

    const float E = sqrtf(__uint_as_float(ctrl[0])) * 1.001f;

    // A fragments (fp16 hi+lo of x) + exact row sum-of-squares for the margin.
    half8 xh[2][2], xl[2][2];
    float xsq[2];
#pragma unroll
    for (int t = 0; t < 2; ++t) {
        const float* px = inputs + (rowbase + t * 16 + m) * DIM;
        float acc = 0.f;
#pragma unroll
        for (int s = 0; s < 2; ++s) {
            const float4* p = (const float4*)(px + q * 8 + s * 32);
            float4 v0 = p[0], v1 = p[1];
            float v[8] = {v0.x, v0.y, v0.z, v0.w, v1.x, v1.y, v1.z, v1.w};
            union { half8 f; _Float16 e[8]; } uh, ul;
#pragma unroll
            for (int j = 0; j < 8; ++j) {
                acc += v[j] * v[j];
                _Float16 h = (_Float16)v[j];
                uh.e[j] = h;
                ul.e[j] = (_Float16)(v[j] - (float)h);
            }
            xh[t][s] = uh.f;
            xl[t][s] = ul.f;
        }
        acc += __shfl_xor(acc, 16);   // reduce across k-quads (same m)
        acc += __shfl_xor(acc, 32);
        xsq[t] = acc;
    }

    float best[2][4], second[2][4];
    int btile[2][4];
#pragma unroll
    for (int t = 0; t < 2; ++t)
#pragma unroll
        for (int r = 0; r < 4; ++r) {
            best[t][r] = -INFINITY;
            second[t][r] = -INFINITY;
            btile[t][r] = 0;
        }

    // Staging: 512 x 16B segments per step; thread handles seg tid and tid+256.
    const int off0 = ((tid >> 3) * RSTRIDE) + (tid & 7) * 16;            // rows 0..31
    const int off1 = (((tid + 256) >> 3) * RSTRIDE) + (tid & 7) * 16;    // rows 32..63
    char* buf0 = lds;
    char* buf1 = lds + BUFB;
    const uint4* gb = (const uint4*)Ch;   // 16B units; 512 per step

    {   // preload step 0
        uint4 a = gb[tid], b = gb[tid + 256];
        *(uint4*)(buf0 + off0) = a;
        *(uint4*)(buf0 + off1) = b;
    }
    __syncthreads();

    // Pipeline state: accB holds the pending (not-yet-selected) tile across
    // the step boundary. Dummy -INF makes the first pending select a no-op.
    f32x4 accA0, accA1, accB0, accB1;
    accB0 = (f32x4){-INFINITY, -INFINITY, -INFINITY, -INFINITY};
    accB1 = accB0;

    for (int step = 0; step < STEPS; ++step) {
        char* curb = (step & 1) ? buf1 : buf0;
        char* nxtb = (step & 1) ? buf0 : buf1;
        uint4 nv0, nv1;
        const bool more = (step + 1) < STEPS;
        if (more) {
            nv0 = gb[(step + 1) * 512 + tid];
            nv1 = gb[(step + 1) * 512 + tid + 256];
        }
        const char* rbase = curb + m * RSTRIDE + q * 16;

        // tile 0 fragment loads (bank X)
        half8 cx0 = *(const half8*)(rbase);
        half8 cx1 = *(const half8*)(rbase + 64);
        float hcx = shc[step * 64 + m];

        // pending selection from previous step's tile 3 (register-only VALU;
        // covers the ds_read latency of the tile-0 fragments above)
        SELECT(accB0, accB1, step * 4 - 1);

        // tile 1 loads (bank Y)
        half8 cy0 = *(const half8*)(rbase + 16 * RSTRIDE);
        half8 cy1 = *(const half8*)(rbase + 16 * RSTRIDE + 64);
        float hcy = shc[step * 64 + 16 + m];

        // tile 0 MFMA
        TILE_MFMA(accA0, accA1, cx0, cx1, hcx);

        // tile 2 loads (bank X regs, consumed by tile-0 MFMAs already issued)
        cx0 = *(const half8*)(rbase + 32 * RSTRIDE);
        cx1 = *(const half8*)(rbase + 32 * RSTRIDE + 64);
        hcx = shc[step * 64 + 32 + m];

        // tile 1 MFMA ∥ select tile 0
        TILE_MFMA(accB0, accB1, cy0, cy1, hcy);
        SELECT(accA0, accA1, step * 4 + 0);

        // tile 3 loads (bank Y)
        cy0 = *(const half8*)(rbase + 48 * RSTRIDE);
        cy1 = *(const half8*)(rbase + 48 * RSTRIDE + 64);
        hcy = shc[step * 64 + 48 + m];

        // tile 2 MFMA ∥ select tile 1
        TILE_MFMA(accA0, accA1, cx0, cx1, hcx);
        SELECT(accB0, accB1, step * 4 + 1);

        // tile 3 MFMA ∥ select tile 2; tile 3 stays pending into next step
        TILE_MFMA(accB0, accB1, cy0, cy1, hcy);
        SELECT(accA0, accA1, step * 4 + 2);

        if (more) {
            *(uint4*)(nxtb + off0) = nv0;
            *(uint4*)(nxtb + off1) = nv1;
        }
        __syncthreads();
    }
    // drain the pipeline: last step's tile 3
    SELECT(accB0, accB1, STEPS * 4 - 1);

    // Cross-lane top-2 merge (16-lane groups), min-index tie-break; gather,
    // write, flag near-ties (rigorous per-row margin) for exact rescue.
#pragma unroll
    for (int t = 0; t < 2; ++t)
#pragma unroll
        for (int r = 0; r < 4; ++r) {
            float b = best[t][r], sc = second[t][r];
            int bi = btile[t][r] * 16 + m;   // reconstruct code index
#pragma unroll
            for (int off = 1; off < 16; off <<= 1) {
                float ob = __shfl_xor(b, off);
                float os = __shfl_xor(sc, off);
                int oi = __shfl_xor(bi, off);
                sc = fmaxf(fmaxf(sc, os), fminf(b, ob));
                if (ob > b || (ob == b && oi < bi)) { b = ob; bi = oi; }
            }
            size_t row = rowbase + t * 16 + q * 4 + r;
            float xs = __shfl(xsq[t], (lane & 48) | (q * 4 + r));
            float marg = 2.0f * (sqrtf(xs) * E + 1e-3f);
            const float4* src = (const float4*)(cb + (size_t)bi * DIM);
            ((float4*)(out + row * DIM))[m] = src[m];
            if (m == 0 && (b - sc) < marg) {
                unsigned pos = atomicAdd(cnt, 1u);
                if (pos < LIST_CAP) list[pos] = (unsigned)row;
            }
        }
}

// ---------------------------------------------------------------------------
// Rescue: unchanged (exact fp32 re-solve, r3/r4-validated arithmetic).
// ---------------------------------------------------------------------------
__global__ __launch_bounds__(256) void vq_rescue(const float* __restrict__ inputs,
                                                 const float* __restrict__ cb,
                                                 const float* __restrict__ hcsq,
                                                 const unsigned* cnt,
                                                 const unsigned* __restrict__ list,
                                                 float* __restrict__ out) {
    unsigned n = *cnt;
    if (n > LIST_CAP) n = LIST_CAP;
    const int lane = threadIdx.x & 63;
    const int sub = lane & 15;  // dim quad
    const int g = lane >> 4;    // code within 4-group
    unsigned gw = blockIdx.x * 4u + (threadIdx.x >> 6);
    unsigned stride = gridDim.x * 4u;
    for (unsigned e = gw; e < n; e += stride) {
        unsigned row = list[e];
        float4 xv = ((const float4*)(inputs + (size_t)row * DIM))[sub];
        float best = -INFINITY;
        int bi = 0;
#pragma unroll 8
        for (int c4 = 0; c4 < NCODES / 4; ++c4) {
            int c = c4 * 4 + g;
            float4 cv = ((const float4*)(cb + (size_t)c * DIM))[sub];
            float p = xv.x * cv.x + xv.y * cv.y + xv.z * cv.z + xv.w * cv.w;
            p += __shfl_xor(p, 1);
            p += __shfl_xor(p, 2);
            p += __shfl_xor(p, 4);
            p += __shfl_xor(p, 8);
            float s = p - hcsq[c];
            if (s > best) { best = s; bi = c; }
        }
#pragma unroll
        for (int off = 16; off < 64; off <<= 1) {
            float ob = __shfl_xor(best, off);
            int oi = __shfl_xor(bi, off);
            if (ob > best || (ob == best && oi < bi)) { best = ob; bi = oi; }
        }
        out[(size_t)row * DIM + lane] = cb[(size_t)bi * DIM + lane];
    }
}

extern "C" void kernel_launch(void* const* d_in, const int* in_sizes, int n_in,
                              void* d_out, int out_size, void* d_ws, size_t ws_size,
                              hipStream_t stream) {
    const float* inputs = (const float*)d_in[0];    // [262144, 64] fp32
    const float* cb = (const float*)d_in[1];        // [1024, 64] fp32
    float* out = (float*)d_out;

    // ws: hcsq f32[1024] | Ch fp16[65536] | ctrl u32[64] | list u32[65536]
    char* ws = (char*)d_ws;
    float* hcsq = (float*)ws;                                   //   4 KiB
    _Float16* Ch = (_Float16*)(ws + 4096);                      // 128 KiB
    unsigned* ctrl = (unsigned*)(ws + 4096 + 131072);           // 256 B slot
    unsigned* list = (unsigned*)(ws + 4096 + 131072 + 256);     // 256 KiB

    hipMemsetAsync(ctrl, 0, 8, stream);     // E2max, cnt
    vq_prep<<<4, 256, 0, stream>>>(cb, hcsq, Ch, ctrl);
    vq_main<<<NROWS / 128, 256, 0, stream>>>(inputs, cb, hcsq, Ch, ctrl,
                                             out, ctrl + 1, list);
    vq_rescue<<<512, 256, 0, stream>>>(inputs, cb, hcsq, ctrl + 1, list, out);
}

// Round 2
// 255.110 us; speedup vs baseline: 1.0260x; 1.0260x over previous
//
#include <hip/hip_runtime.h>

#define NROWS   262144
#define NCODES  1024
#define DIM     64
#define LIST_CAP 65536u
#define STEPS   16       // 1024 codes / 64 per step
#define STEPB   8192     // fp16 codebook bytes per step: 64 codes x 128 B, linear

typedef _Float16 half8 __attribute__((ext_vector_type(8)));
typedef __attribute__((ext_vector_type(4))) float f32x4;

#define MFMA16(acc, a, b) acc = __builtin_amdgcn_mfma_f32_16x16x32_f16(a, b, acc, 0, 0, 0)

// global_load_lds: LDS dest is wave-uniform base + lane*16 (linear). Bank
// conflicts on the read side are handled by pre-swizzling Ch in GLOBAL memory
// (vq_prep) and applying the same XOR on the LDS read (rule: both-sides).
typedef __attribute__((address_space(1))) const void gconst_void;
typedef __attribute__((address_space(3))) void lds_void;
#define GLOAD16(gp, lp) \
    __builtin_amdgcn_global_load_lds((gconst_void*)(gp), (lds_void*)(lp), 16, 0, 0)

// ---------------------------------------------------------------------------
// Prep: arithmetic bit-identical to the validated version (sequential chain
// sums, true residual). ONLY change: the fp16 chunk store offset is XOR-
// swizzled (chunk j of code k lands at byte k*128 + ((j ^ (k&7))<<4)) so the
// main kernel can stage linearly via global_load_lds and read conflict-free.
// ctrl[0] = max ||c - fp16(c)||^2 bits (atomicMax), ctrl[1] = flag counter.
// ---------------------------------------------------------------------------
__global__ __launch_bounds__(256) void vq_prep(const float* __restrict__ cb,
                                               float* __restrict__ hcsq,
                                               _Float16* __restrict__ Ch,
                                               unsigned* ctrl) {
    const int k = blockIdx.x * 256 + threadIdx.x;   // 0..1023
    const float4* row = (const float4*)(cb + (size_t)k * DIM);
    char* co = (char*)Ch + (size_t)k * 128;
    const int sw = (k & 7) << 4;
    float s = 0.f, r2 = 0.f;
#pragma unroll
    for (int i = 0; i < 8; ++i) {
        float4 a = row[2 * i], b = row[2 * i + 1];
        float v[8] = {a.x, a.y, a.z, a.w, b.x, b.y, b.z, b.w};
        union { half8 f; _Float16 e[8]; } uh;
#pragma unroll
        for (int j = 0; j < 8; ++j) {
            float c = v[j];
            s += c * c;                    // sequential chain (matches r4/r1)
            _Float16 h = (_Float16)c;      // RNE
            uh.e[j] = h;
            float d = c - (float)h;        // true residual
            r2 += d * d;
        }
        *(half8*)(co + ((i << 4) ^ sw)) = uh.f;   // swizzled chunk store
    }
    hcsq[k] = 0.5f * s;
    float w = r2;
#pragma unroll
    for (int off = 1; off < 64; off <<= 1) w = fmaxf(w, __shfl_xor(w, off));
    if ((threadIdx.x & 63) == 0) atomicMax(ctrl + 0, __float_as_uint(w));
}

// ---------------------------------------------------------------------------
// Main. Same score math / margins as the validated kernel. Round-2 structure:
//   - 16 rows/wave (64 rows/block, grid 4096): halves xh/xl, best/second/
//     btile, acc register arrays -> target <=64 VGPRs = 8 waves/SIMD (m69
//     occupancy cliff). __launch_bounds__(256,8) pins the allocator.
//   - Codebook staging via global_load_lds (linear dest, pre-swizzled global
//     source, XOR on read): kills the 8 staging VGPRs + ds_writes.
//   - LDS = 2*8192 + 4096 = 20480 B -> exactly 8 blocks/CU in 160 KiB.
//   - Lag-1 select pipeline (accA/accB) kept; -hc folded into acc init;
//     wave-uniform tile index tracked (code = tile*16 + m in epilogue).
// ---------------------------------------------------------------------------
#define SELECT(acc, tl)                                                     \
    {                                                                       \
        const int _tl = (tl);                                               \
        _Pragma("unroll")                                                   \
        for (int r = 0; r < 4; ++r) {                                       \
            float s0 = (acc)[r];                                            \
            bool g = s0 > best[r];                                          \
            second[r] = __builtin_amdgcn_fmed3f(s0, best[r], second[r]);    \
            best[r] = g ? s0 : best[r];                                     \
            btile[r] = g ? _tl : btile[r];                                  \
        }                                                                   \
    }

__global__ __launch_bounds__(256, 8) void vq_main(const float* __restrict__ inputs,
                                                  const float* __restrict__ cb,
                                                  const float* __restrict__ hcsq,
                                                  const _Float16* __restrict__ Ch,
                                                  const unsigned* ctrl,
                                                  float* __restrict__ out,
                                                  unsigned* cnt,
                                                  unsigned* __restrict__ list) {
    __shared__ __align__(1024) char lds[2 * STEPB];
    __shared__ float shc[NCODES];
    const int tid = threadIdx.x;
    const int lane = tid & 63;
    const int wave = tid >> 6;
    const int m = lane & 15;   // A row-in-tile / B code-in-tile / D col
    const int q = lane >> 4;   // k-quad
    const size_t rowbase = (size_t)blockIdx.x * 64 + (size_t)wave * 16;

    for (int i = tid; i < NCODES; i += 256) shc[i] = hcsq[i];

    const float E = sqrtf(__uint_as_float(ctrl[0])) * 1.001f;

    // A fragments (fp16 hi+lo of x) + exact row sum-of-squares for the margin.
    half8 xh[2], xl[2];
    float xsq;
    {
        const float* px = inputs + (rowbase + m) * DIM;
        float acc = 0.f;
#pragma unroll
        for (int s = 0; s < 2; ++s) {
            const float4* p = (const float4*)(px + q * 8 + s * 32);
            float4 v0 = p[0], v1 = p[1];
            float v[8] = {v0.x, v0.y, v0.z, v0.w, v1.x, v1.y, v1.z, v1.w};
            union { half8 f; _Float16 e[8]; } uh, ul;
#pragma unroll
            for (int j = 0; j < 8; ++j) {
                acc += v[j] * v[j];
                _Float16 h = (_Float16)v[j];
                uh.e[j] = h;
                ul.e[j] = (_Float16)(v[j] - (float)h);
            }
            xh[s] = uh.f;
            xl[s] = ul.f;
        }
        acc += __shfl_xor(acc, 16);   // reduce across k-quads (same m)
        acc += __shfl_xor(acc, 32);
        xsq = acc;
    }

    float best[4], second[4];
    int btile[4];
#pragma unroll
    for (int r = 0; r < 4; ++r) {
        best[r] = -INFINITY;
        second[r] = -INFINITY;
        btile[r] = 0;
    }

    // Staging: per step 8192 B; wave w copies [w*2048, w*2048+2048) with two
    // wave-wide global_load_lds (64 lanes x 16 B each).
    const char* gB = (const char*)Ch;
    {   // preload step 0 into buffer 0
        const char* gs = gB + wave * 2048 + lane * 16;
        char* ld = lds + wave * 2048;
        GLOAD16(gs, ld);
        GLOAD16(gs + 1024, ld + 1024);
    }
    __syncthreads();

    // Read-side swizzle: chunk j of row m lives at m*128 + ((j ^ (m&7))<<4).
    // Needed chunks are j=q and j=q+4 -> byte offsets offA and offA^64.
    const int offA = ((q ^ (m & 7)) << 4);
    const int offB = offA ^ 64;

    // Lag-1 pipeline: accB carries the pending tile across the step boundary.
    // Dummy -INF makes the first pending select a provable no-op.
    f32x4 accA, accB;
    accB = (f32x4){-INFINITY, -INFINITY, -INFINITY, -INFINITY};

    for (int step = 0; step < STEPS; ++step) {
        char* curb = lds + (step & 1) * STEPB;
        char* nxtb = lds + ((step + 1) & 1) * STEPB;
        if (step + 1 < STEPS) {   // issue next-step staging early
            const char* gs = gB + (step + 1) * STEPB + wave * 2048 + lane * 16;
            char* ld = nxtb + wave * 2048;
            GLOAD16(gs, ld);
            GLOAD16(gs + 1024, ld + 1024);
        }
        const char* rb = curb + m * 128;
        const int hbase = step * 64 + m;

        // tile 0
        half8 b0 = *(const half8*)(rb + offA);
        half8 b1 = *(const half8*)(rb + offB);
        float hc = shc[hbase];
        SELECT(accB, step * 4 - 1);   // prev step's tile 3 (covers ds_reads)
        accA = (f32x4){-hc, -hc, -hc, -hc};
        MFMA16(accA, xh[0], b0); MFMA16(accA, xh[1], b1);
        MFMA16(accA, xl[0], b0); MFMA16(accA, xl[1], b1);

        // tile 1
        b0 = *(const half8*)(rb + 2048 + offA);
        b1 = *(const half8*)(rb + 2048 + offB);
        hc = shc[hbase + 16];
        SELECT(accA, step * 4 + 0);
        accB = (f32x4){-hc, -hc, -hc, -hc};
        MFMA16(accB, xh[0], b0); MFMA16(accB, xh[1], b1);
        MFMA16(accB, xl[0], b0); MFMA16(accB, xl[1], b1);

        // tile 2
        b0 = *(const half8*)(rb + 4096 + offA);
        b1 = *(const half8*)(rb + 4096 + offB);
        hc = shc[hbase + 32];
        SELECT(accB, step * 4 + 1);
        accA = (f32x4){-hc, -hc, -hc, -hc};
        MFMA16(accA, xh[0], b0); MFMA16(accA, xh[1], b1);
        MFMA16(accA, xl[0], b0); MFMA16(accA, xl[1], b1);

        // tile 3 (stays pending into next step)
        b0 = *(const half8*)(rb + 6144 + offA);
        b1 = *(const half8*)(rb + 6144 + offB);
        hc = shc[hbase + 48];
        SELECT(accA, step * 4 + 2);
        accB = (f32x4){-hc, -hc, -hc, -hc};
        MFMA16(accB, xh[0], b0); MFMA16(accB, xh[1], b1);
        MFMA16(accB, xl[0], b0); MFMA16(accB, xl[1], b1);

        __syncthreads();   // staging drained (vmcnt) + curb consumption done
    }
    SELECT(accB, STEPS * 4 - 1);   // drain last pending tile

    // Cross-lane top-2 merge (16-lane groups), min-index tie-break; gather,
    // write, flag near-ties (rigorous per-row margin) for exact rescue.
#pragma unroll
    for (int r = 0; r < 4; ++r) {
        float b = best[r], sc = second[r];
        int bi = btile[r] * 16 + m;   // reconstruct code index
#pragma unroll
        for (int off = 1; off < 16; off <<= 1) {
            float ob = __shfl_xor(b, off);
            float os = __shfl_xor(sc, off);
            int oi = __shfl_xor(bi, off);
            sc = fmaxf(fmaxf(sc, os), fminf(b, ob));
            if (ob > b || (ob == b && oi < bi)) { b = ob; bi = oi; }
        }
        size_t row = rowbase + q * 4 + r;
        float xs = __shfl(xsq, (lane & 48) | (q * 4 + r));
        float marg = 2.0f * (sqrtf(xs) * E + 1e-3f);
        const float4* src = (const float4*)(cb + (size_t)bi * DIM);
        ((float4*)(out + row * DIM))[m] = src[m];
        if (m == 0 && (b - sc) < marg) {
            unsigned pos = atomicAdd(cnt, 1u);
            if (pos < LIST_CAP) list[pos] = (unsigned)row;
        }
    }
}

// ---------------------------------------------------------------------------
// Rescue: unchanged (exact fp32 re-solve, validated arithmetic).
// ---------------------------------------------------------------------------
__global__ __launch_bounds__(256) void vq_rescue(const float* __restrict__ inputs,
                                                 const float* __restrict__ cb,
                                                 const float* __restrict__ hcsq,
                                                 const unsigned* cnt,
                                                 const unsigned* __restrict__ list,
                                                 float* __restrict__ out) {
    unsigned n = *cnt;
    if (n > LIST_CAP) n = LIST_CAP;
    const int lane = threadIdx.x & 63;
    const int sub = lane & 15;  // dim quad
    const int g = lane >> 4;    // code within 4-group
    unsigned gw = blockIdx.x * 4u + (threadIdx.x >> 6);
    unsigned stride = gridDim.x * 4u;
    for (unsigned e = gw; e < n; e += stride) {
        unsigned row = list[e];
        float4 xv = ((const float4*)(inputs + (size_t)row * DIM))[sub];
        float best = -INFINITY;
        int bi = 0;
#pragma unroll 8
        for (int c4 = 0; c4 < NCODES / 4; ++c4) {
            int c = c4 * 4 + g;
            float4 cv = ((const float4*)(cb + (size_t)c * DIM))[sub];
            float p = xv.x * cv.x + xv.y * cv.y + xv.z * cv.z + xv.w * cv.w;
            p += __shfl_xor(p, 1);
            p += __shfl_xor(p, 2);
            p += __shfl_xor(p, 4);
            p += __shfl_xor(p, 8);
            float s = p - hcsq[c];
            if (s > best) { best = s; bi = c; }
        }
#pragma unroll
        for (int off = 16; off < 64; off <<= 1) {
            float ob = __shfl_xor(best, off);
            int oi = __shfl_xor(bi, off);
            if (ob > best || (ob == best && oi < bi)) { best = ob; bi = oi; }
        }
        out[(size_t)row * DIM + lane] = cb[(size_t)bi * DIM + lane];
    }
}

extern "C" void kernel_launch(void* const* d_in, const int* in_sizes, int n_in,
                              void* d_out, int out_size, void* d_ws, size_t ws_size,
                              hipStream_t stream) {
    const float* inputs = (const float*)d_in[0];    // [262144, 64] fp32
    const float* cb = (const float*)d_in[1];        // [1024, 64] fp32
    float* out = (float*)d_out;

    // ws: hcsq f32[1024] | Ch fp16[65536] (swizzled) | ctrl u32[64] | list u32[65536]
    char* ws = (char*)d_ws;
    float* hcsq = (float*)ws;                                   //   4 KiB
    _Float16* Ch = (_Float16*)(ws + 4096);                      // 128 KiB
    unsigned* ctrl = (unsigned*)(ws + 4096 + 131072);           // 256 B slot
    unsigned* list = (unsigned*)(ws + 4096 + 131072 + 256);     // 256 KiB

    hipMemsetAsync(ctrl, 0, 8, stream);     // E2max, cnt
    vq_prep<<<4, 256, 0, stream>>>(cb, hcsq, Ch, ctrl);
    vq_main<<<NROWS / 64, 256, 0, stream>>>(inputs, cb, hcsq, Ch, ctrl,
                                            out, ctrl + 1, list);
    vq_rescue<<<512, 256, 0, stream>>>(inputs, cb, hcsq, ctrl + 1, list, out);
}

// Round 3
// 252.879 us; speedup vs baseline: 1.0351x; 1.0088x over previous
//
#include <hip/hip_runtime.h>

#define NROWS   262144
#define NCODES  1024
#define DIM     64
#define LIST_CAP 65536u
#define NTILES  64       // 16-code MFMA tiles covering 1024 codes
#define TILEB   2048     // bytes per tile in fragment layout (2 x 1024)
#define PADT    4        // prefetch overrun pad (tiles 64..67 read, never used)

typedef _Float16 half8 __attribute__((ext_vector_type(8)));
typedef __attribute__((ext_vector_type(4))) float f32x4;

#define MFMA16(acc, a, b) acc = __builtin_amdgcn_mfma_f32_16x16x32_f16(a, b, acc, 0, 0, 0)

// ---------------------------------------------------------------------------
// Prep: arithmetic bit-identical to the validated version (sequential chain
// sums, true residual, RNE fp16). ONLY change: the fp16 codebook is stored in
// MFMA B-fragment order so vq_main can load fragments global->VGPR with
// perfectly coalesced wave-wide 16B/lane loads:
//   tile T (codes T*16+m), lane = q*16+m, j in {0,1}:
//   byte addr = T*2048 + j*1024 + (q*16+m)*16  holds chunk (q+4j) of the code.
// ctrl[0] = max ||c - fp16(c)||^2 bits (atomicMax), ctrl[1] = flag counter.
// ---------------------------------------------------------------------------
__global__ __launch_bounds__(256) void vq_prep(const float* __restrict__ cb,
                                               float* __restrict__ hcsq,
                                               _Float16* __restrict__ Ch,
                                               unsigned* ctrl) {
    const int k = blockIdx.x * 256 + threadIdx.x;   // 0..1023
    const float4* row = (const float4*)(cb + (size_t)k * DIM);
    char* base = (char*)Ch + (size_t)(k >> 4) * TILEB + (size_t)(k & 15) * 16;
    float s = 0.f, r2 = 0.f;
#pragma unroll
    for (int i = 0; i < 8; ++i) {   // chunk i: halves i*8..i*8+7
        float4 a = row[2 * i], b = row[2 * i + 1];
        float v[8] = {a.x, a.y, a.z, a.w, b.x, b.y, b.z, b.w};
        union { half8 f; _Float16 e[8]; } uh;
#pragma unroll
        for (int j = 0; j < 8; ++j) {
            float c = v[j];
            s += c * c;                    // sequential chain (matches r4/r1)
            _Float16 h = (_Float16)c;      // RNE
            uh.e[j] = h;
            float d = c - (float)h;        // true residual
            r2 += d * d;
        }
        // chunk i -> j = i>>2 slot, q-position = i&3
        *(half8*)(base + ((i >> 2) << 10) + ((i & 3) << 8)) = uh.f;
    }
    hcsq[k] = 0.5f * s;
    float w = r2;
#pragma unroll
    for (int off = 1; off < 64; off <<= 1) w = fmaxf(w, __shfl_xor(w, off));
    if ((threadIdx.x & 63) == 0) atomicMax(ctrl + 0, __float_as_uint(w));
}

// ---------------------------------------------------------------------------
// Main. Same score math / margins as the validated kernels (fp16 hi+lo
// 2-term, -hc folded into acc init, fused top-2, margin 2(||x||E+1e-3)).
// Round-3 structure: NO per-step barrier, NO LDS codebook staging. B-frags
// stream global->VGPR from the L2-resident fragment-ordered codebook via a
// 4-tile rotating register pipeline (compiler emits counted vmcnt). LDS holds
// only the negated half-square table (4 KB). 32 rows/wave, grid 2048.
// ---------------------------------------------------------------------------
#define SELECT(aa, ab, tl)                                                        \
    {                                                                             \
        const int _tl = (tl);                                                     \
        _Pragma("unroll")                                                         \
        for (int r = 0; r < 4; ++r) {                                             \
            float s0 = (aa)[r];                                                   \
            bool g0 = s0 > best[0][r];                                            \
            second[0][r] = __builtin_amdgcn_fmed3f(s0, best[0][r], second[0][r]); \
            best[0][r] = g0 ? s0 : best[0][r];                                    \
            btile[0][r] = g0 ? _tl : btile[0][r];                                 \
            float s1 = (ab)[r];                                                   \
            bool g1 = s1 > best[1][r];                                            \
            second[1][r] = __builtin_amdgcn_fmed3f(s1, best[1][r], second[1][r]); \
            best[1][r] = g1 ? s1 : best[1][r];                                    \
            btile[1][r] = g1 ? _tl : btile[1][r];                                 \
        }                                                                         \
    }

// One tile: select the OTHER acc pair (lag-1), init this pair to -hc, 8 MFMA
// from fragment regs fA/fB, then refill fA/fB with the tile 4 ahead.
#define PHASE(fA, fB, a0, a1, o0, o1, TT)                     \
    {                                                         \
        const int _T = (TT);                                  \
        float nh = nshc[_T * 16 + m];                         \
        SELECT(o0, o1, _T - 1);                               \
        a0 = (f32x4){nh, nh, nh, nh};                         \
        a1 = a0;                                              \
        MFMA16(a0, xh[0][0], fA); MFMA16(a1, xh[1][0], fA);   \
        MFMA16(a0, xh[0][1], fB); MFMA16(a1, xh[1][1], fB);   \
        MFMA16(a0, xl[0][0], fA); MFMA16(a1, xl[1][0], fA);   \
        MFMA16(a0, xl[0][1], fB); MFMA16(a1, xl[1][1], fB);   \
        fA = *(const half8*)(gpre);                           \
        fB = *(const half8*)(gpre + 1024);                    \
        gpre += TILEB;                                        \
    }

__global__ __launch_bounds__(256, 4) void vq_main(const float* __restrict__ inputs,
                                                  const float* __restrict__ cb,
                                                  const float* __restrict__ hcsq,
                                                  const _Float16* __restrict__ Ch,
                                                  const unsigned* ctrl,
                                                  float* __restrict__ out,
                                                  unsigned* cnt,
                                                  unsigned* __restrict__ list) {
    __shared__ float nshc[NCODES];   // negated 0.5||c||^2 (4 KB, loaded once)
    const int tid = threadIdx.x;
    const int lane = tid & 63;
    const int wave = tid >> 6;
    const int m = lane & 15;   // A row-in-tile / B code-in-tile / D col
    const int q = lane >> 4;   // k-quad
    const size_t rowbase = (size_t)blockIdx.x * 128 + (size_t)wave * 32;

    for (int i = tid; i < NCODES; i += 256) nshc[i] = -hcsq[i];

    const float E = sqrtf(__uint_as_float(ctrl[0])) * 1.001f;

    // A fragments (fp16 hi+lo of x) + exact row sum-of-squares for the margin.
    half8 xh[2][2], xl[2][2];
    float xsq[2];
#pragma unroll
    for (int t = 0; t < 2; ++t) {
        const float* px = inputs + (rowbase + t * 16 + m) * DIM;
        float acc = 0.f;
#pragma unroll
        for (int s = 0; s < 2; ++s) {
            const float4* p = (const float4*)(px + q * 8 + s * 32);
            float4 v0 = p[0], v1 = p[1];
            float v[8] = {v0.x, v0.y, v0.z, v0.w, v1.x, v1.y, v1.z, v1.w};
            union { half8 f; _Float16 e[8]; } uh, ul;
#pragma unroll
            for (int j = 0; j < 8; ++j) {
                acc += v[j] * v[j];
                _Float16 h = (_Float16)v[j];
                uh.e[j] = h;
                ul.e[j] = (_Float16)(v[j] - (float)h);
            }
            xh[t][s] = uh.f;
            xl[t][s] = ul.f;
        }
        acc += __shfl_xor(acc, 16);   // reduce across k-quads (same m)
        acc += __shfl_xor(acc, 32);
        xsq[t] = acc;
    }
    __syncthreads();   // nshc ready; the ONLY block barrier

    float best[2][4], second[2][4];
    int btile[2][4];
#pragma unroll
    for (int t = 0; t < 2; ++t)
#pragma unroll
        for (int r = 0; r < 4; ++r) {
            best[t][r] = -INFINITY;
            second[t][r] = -INFINITY;
            btile[t][r] = 0;
        }

    // 4-tile rotating register prefetch pipeline over the fragment-ordered
    // codebook. Each lane reads its own 16B fragment pair per tile; a wave's
    // 64 lanes cover one tile's 2 KB with two coalesced 1 KB loads.
    const char* gL = (const char*)Ch + (size_t)lane * 16;
    half8 f0a = *(const half8*)(gL);
    half8 f0b = *(const half8*)(gL + 1024);
    half8 f1a = *(const half8*)(gL + TILEB);
    half8 f1b = *(const half8*)(gL + TILEB + 1024);
    half8 f2a = *(const half8*)(gL + 2 * TILEB);
    half8 f2b = *(const half8*)(gL + 2 * TILEB + 1024);
    half8 f3a = *(const half8*)(gL + 3 * TILEB);
    half8 f3b = *(const half8*)(gL + 3 * TILEB + 1024);
    const char* gpre = gL + 4 * TILEB;

    // Lag-1 select pipeline; dummy -INF makes the first select a no-op.
    f32x4 accA0, accA1, accB0, accB1;
    accB0 = (f32x4){-INFINITY, -INFINITY, -INFINITY, -INFINITY};
    accB1 = accB0;

    for (int it = 0; it < 16; ++it) {
        const int T = it * 4;
        PHASE(f0a, f0b, accA0, accA1, accB0, accB1, T + 0);
        PHASE(f1a, f1b, accB0, accB1, accA0, accA1, T + 1);
        PHASE(f2a, f2b, accA0, accA1, accB0, accB1, T + 2);
        PHASE(f3a, f3b, accB0, accB1, accA0, accA1, T + 3);
    }
    SELECT(accB0, accB1, NTILES - 1);   // drain last pending tile

    // Cross-lane top-2 merge (16-lane groups), min-index tie-break; gather,
    // write, flag near-ties (rigorous per-row margin) for exact rescue.
#pragma unroll
    for (int t = 0; t < 2; ++t)
#pragma unroll
        for (int r = 0; r < 4; ++r) {
            float b = best[t][r], sc = second[t][r];
            int bi = btile[t][r] * 16 + m;   // reconstruct code index
#pragma unroll
            for (int off = 1; off < 16; off <<= 1) {
                float ob = __shfl_xor(b, off);
                float os = __shfl_xor(sc, off);
                int oi = __shfl_xor(bi, off);
                sc = fmaxf(fmaxf(sc, os), fminf(b, ob));
                if (ob > b || (ob == b && oi < bi)) { b = ob; bi = oi; }
            }
            size_t row = rowbase + t * 16 + q * 4 + r;
            float xs = __shfl(xsq[t], (lane & 48) | (q * 4 + r));
            float marg = 2.0f * (sqrtf(xs) * E + 1e-3f);
            const float4* src = (const float4*)(cb + (size_t)bi * DIM);
            ((float4*)(out + row * DIM))[m] = src[m];
            if (m == 0 && (b - sc) < marg) {
                unsigned pos = atomicAdd(cnt, 1u);
                if (pos < LIST_CAP) list[pos] = (unsigned)row;
            }
        }
}

// ---------------------------------------------------------------------------
// Rescue: unchanged (exact fp32 re-solve, validated arithmetic).
// ---------------------------------------------------------------------------
__global__ __launch_bounds__(256) void vq_rescue(const float* __restrict__ inputs,
                                                 const float* __restrict__ cb,
                                                 const float* __restrict__ hcsq,
                                                 const unsigned* cnt,
                                                 const unsigned* __restrict__ list,
                                                 float* __restrict__ out) {
    unsigned n = *cnt;
    if (n > LIST_CAP) n = LIST_CAP;
    const int lane = threadIdx.x & 63;
    const int sub = lane & 15;  // dim quad
    const int g = lane >> 4;    // code within 4-group
    unsigned gw = blockIdx.x * 4u + (threadIdx.x >> 6);
    unsigned stride = gridDim.x * 4u;
    for (unsigned e = gw; e < n; e += stride) {
        unsigned row = list[e];
        float4 xv = ((const float4*)(inputs + (size_t)row * DIM))[sub];
        float best = -INFINITY;
        int bi = 0;
#pragma unroll 8
        for (int c4 = 0; c4 < NCODES / 4; ++c4) {
            int c = c4 * 4 + g;
            float4 cv = ((const float4*)(cb + (size_t)c * DIM))[sub];
            float p = xv.x * cv.x + xv.y * cv.y + xv.z * cv.z + xv.w * cv.w;
            p += __shfl_xor(p, 1);
            p += __shfl_xor(p, 2);
            p += __shfl_xor(p, 4);
            p += __shfl_xor(p, 8);
            float s = p - hcsq[c];
            if (s > best) { best = s; bi = c; }
        }
#pragma unroll
        for (int off = 16; off < 64; off <<= 1) {
            float ob = __shfl_xor(best, off);
            int oi = __shfl_xor(bi, off);
            if (ob > best || (ob == best && oi < bi)) { best = ob; bi = oi; }
        }
        out[(size_t)row * DIM + lane] = cb[(size_t)bi * DIM + lane];
    }
}

extern "C" void kernel_launch(void* const* d_in, const int* in_sizes, int n_in,
                              void* d_out, int out_size, void* d_ws, size_t ws_size,
                              hipStream_t stream) {
    const float* inputs = (const float*)d_in[0];    // [262144, 64] fp32
    const float* cb = (const float*)d_in[1];        // [1024, 64] fp32
    float* out = (float*)d_out;

    // ws: hcsq f32[1024] | Ch fp16 fragment-order [68 tiles x 2048 B incl.
    // 4-tile prefetch pad] | ctrl u32[64] | list u32[65536]
    char* ws = (char*)d_ws;
    float* hcsq = (float*)ws;                                       //   4 KiB
    _Float16* Ch = (_Float16*)(ws + 4096);                          // 136 KiB
    unsigned* ctrl = (unsigned*)(ws + 4096 + (NTILES + PADT) * TILEB);
    unsigned* list = (unsigned*)(ws + 4096 + (NTILES + PADT) * TILEB + 256);

    hipMemsetAsync(ctrl, 0, 8, stream);     // E2max, cnt
    vq_prep<<<4, 256, 0, stream>>>(cb, hcsq, Ch, ctrl);
    vq_main<<<NROWS / 128, 256, 0, stream>>>(inputs, cb, hcsq, Ch, ctrl,
                                             out, ctrl + 1, list);
    vq_rescue<<<512, 256, 0, stream>>>(inputs, cb, hcsq, ctrl + 1, list, out);
}